// Round 18
// baseline (91.426 us; speedup 1.0000x reference)
//
#include <hip/hip_runtime.h>

#define NB   32
#define NC   3
#define NH   512
#define NW   512
#define KS   25
#define HALF 12
#define NS   60
#define PLN  (NH * NW)        // 262144
#define NPL  (NB * NC)        // 96
#define BAND 32               // output rows per block
#define HROWS (BAND + 2 * HALF)   // 56 h-blurred rows staged in LDS
#define NBANDS (NH / BAND)    // 16

typedef _Float16 half4 __attribute__((ext_vector_type(4)));
typedef _Float16 half8 __attribute__((ext_vector_type(8)));

// ---- workspace layout ----
#define WTS_OFF   ((size_t)0)
#define WTS_BYTES ((size_t)4096)
#define ORD_OFF   (WTS_OFF + WTS_BYTES)
#define ORD_BYTES ((size_t)512)               // 96 ints, padded
#define TR_OFF    (ORD_OFF + ORD_BYTES)
#define TR_BYTES  ((size_t)512)               // 32 x {t_lo,t_hi}
#define NL_OFF    (TR_OFF + TR_BYTES)
#define NL_BYTES  ((size_t)NB * NW * 4)
#define PK_OFF    (NL_OFF + NL_BYTES)
#define PK_BYTES  ((size_t)NB * NW * NS * 4)
#define WS_NEED   (PK_OFF + PK_BYTES)                 // ~4.3 MB

__device__ __forceinline__ float clip01(float v) { return fminf(fmaxf(v, 0.f), 1.f); }

struct PParams {
  int f1, f2, f3, f4;
  float intensity, cx, cy, rxi, ryi;
  float oy0, oy1, ox0, ox1;
  float log1ma;
  float thr_lo, thr_hi;
};

__device__ __forceinline__ PParams load_params(
    int b, const int* __restrict__ flags, const float* __restrict__ glare_u,
    const float* __restrict__ occ_u, const float* __restrict__ rain_alpha_u,
    const float* __restrict__ noise_amt_u)
{
  PParams P;
  P.f1 = flags[b * 5 + 1] > 0;
  P.f2 = flags[b * 5 + 2] > 0;
  P.f3 = flags[b * 5 + 3] > 0;
  P.f4 = flags[b * 5 + 4] > 0;
  float g0 = glare_u[b * 5 + 0], g1 = glare_u[b * 5 + 1], g2 = glare_u[b * 5 + 2],
        g3 = glare_u[b * 5 + 3], g4 = glare_u[b * 5 + 4];
  P.intensity = 0.4f + 0.5f * g0;
  P.rxi = 1.f / ((0.1f + 0.25f * g1) * 256.f);
  P.ryi = 1.f / ((0.1f + 0.25f * g2) * 256.f);
  P.cx = (0.2f + 0.6f * g3) * 512.f;
  P.cy = (0.2f + 0.6f * g4) * 512.f;
  float o0 = occ_u[b * 4 + 0], o1 = occ_u[b * 4 + 1],
        o2 = occ_u[b * 4 + 2], o3 = occ_u[b * 4 + 3];
  float ph = floorf(512.f * (0.1f + 0.3f * o0));
  float pw = floorf(512.f * (0.1f + 0.3f * o1));
  P.oy0 = floorf(o2 * (512.f - ph)); P.oy1 = P.oy0 + ph;
  P.ox0 = floorf(o3 * (512.f - pw)); P.ox1 = P.ox0 + pw;
  P.log1ma = log2f(1.f - (0.15f + 0.35f * rain_alpha_u[b]));
  float half_amt = 0.5f * (0.01f + 0.07f * noise_amt_u[b]);
  P.thr_lo = half_amt; P.thr_hi = 1.f - half_amt;
  return P;
}

// ---- prep: rain lists + blur weights + LPT order + adaptive tap range ----
__global__ void prep_kernel(const float* __restrict__ rain_u,
                            const float* __restrict__ rain_n_u,
                            const float* __restrict__ sigma_u,
                            const int* __restrict__ flags,
                            int* __restrict__ nlist,
                            unsigned* __restrict__ packed,
                            float* __restrict__ wts,
                            int* __restrict__ order,
                            int* __restrict__ trange)
{
  if (blockIdx.x == 64) {
    int b = threadIdx.x;
    if (b < NB) {
      float sig = 1.f + 3.f * sigma_u[b];
      float ninv = -1.f / (2.f * sig * sig);
      float w[KS]; float s = 0.f;
      #pragma unroll
      for (int j = 0; j < KS; ++j) {
        float d = (float)j - 12.f;
        w[j] = __expf(d * d * ninv);
        s += w[j];
      }
      float inv = 1.f / s;
      #pragma unroll
      for (int j = 0; j < KS; ++j) { w[j] *= inv; wts[b * 28 + j] = w[j]; }
      // adaptive support: skip taps whose per-side mass < 5e-4 (error <=1e-3)
      float acc = 0.f; int t_lo = 0;
      while (t_lo < 12 && acc + w[t_lo] < 5e-4f) { acc += w[t_lo]; ++t_lo; }
      float acc2 = 0.f; int t_hi = 24;
      while (t_hi > 12 && acc2 + w[t_hi] < 5e-4f) { acc2 += w[t_hi]; --t_hi; }
      trange[b * 2 + 0] = t_lo;
      trange[b * 2 + 1] = t_hi;
    }
    // LPT plane ordering: blur planes first.
    if (threadIdx.x == 64) {
      int pos = 0;
      for (int pl = 0; pl < NPL; ++pl)
        if (flags[(pl / 3) * 5] > 0) order[pos++] = pl;
      for (int pl = 0; pl < NPL; ++pl)
        if (flags[(pl / 3) * 5] <= 0) order[pos++] = pl;
    }
    return;
  }
  int t = blockIdx.x * 256 + threadIdx.x;
  if (t >= NB * NW) return;
  int b = t >> 9, wcol = t & 511;
  float n = floorf(20.f + 41.f * rain_n_u[b]);
  float wf = (float)wcol;
  int cnt = 0;
  for (int s = 0; s < NS; ++s) {
    if ((float)s < n) {
      float xc = floorf(rain_u[(b * NS + s) * 3 + 0] * 512.f);
      if (wf >= xc - 1.f && wf <= xc) {
        float y0 = floorf(rain_u[(b * NS + s) * 3 + 1] * 256.f);
        float y1 = 256.f + floorf(rain_u[(b * NS + s) * 3 + 2] * 256.f);
        packed[t * NS + cnt] = (((unsigned)y0) << 16) | (unsigned)y1;
        ++cnt;
      }
    }
  }
  nlist[t] = cnt;
}

// ---- chain on a 4-col x KR-row quad block ----
template<int KR>
__device__ __forceinline__ void chain_quadN(
    float (&a)[KR][4], const PParams& P, int b, int gx0, int gy0,
    const float* __restrict__ np_plane, const int* __restrict__ nlist,
    const unsigned* __restrict__ packed, float* __restrict__ op_plane)
{
  if (P.f1) {
    float dx2[4];
    #pragma unroll
    for (int c = 0; c < 4; ++c) {
      float dx = ((float)(gx0 + c) - P.cx) * P.rxi;
      dx2[c] = dx * dx;
    }
    #pragma unroll
    for (int k = 0; k < KR; ++k) {
      float dy = ((float)(gy0 + k) - P.cy) * P.ryi;
      float dy2 = dy * dy;
      #pragma unroll
      for (int c = 0; c < 4; ++c) {
        float g = __expf(-(dx2[c] + dy2));
        a[k][c] = clip01(a[k][c] + P.intensity * g);
      }
    }
  }
  if (P.f2) {
    #pragma unroll
    for (int c = 0; c < 4; ++c) {
      float fx = (float)(gx0 + c);
      if (fx >= P.ox0 && fx < P.ox1) {
        #pragma unroll
        for (int k = 0; k < KR; ++k) {
          float fy = (float)(gy0 + k);
          if (fy >= P.oy0 && fy < P.oy1) a[k][c] = 0.f;
        }
      }
    }
  }
  if (P.f3) {
    #pragma unroll
    for (int c = 0; c < 4; ++c) {
      int base = b * NW + gx0 + c;
      int n = nlist[base];
      if (n > 0) {
        float cnt[KR];
        #pragma unroll
        for (int k = 0; k < KR; ++k) cnt[k] = 0.f;
        for (int j = 0; j < n; ++j) {
          unsigned p = packed[base * NS + j];
          float y0 = (float)(p >> 16), y1 = (float)(p & 0xffffu);
          #pragma unroll
          for (int k = 0; k < KR; ++k) {
            float fy = (float)(gy0 + k);
            cnt[k] += (fy >= y0 && fy < y1) ? 1.f : 0.f;
          }
        }
        #pragma unroll
        for (int k = 0; k < KR; ++k) {
          if (cnt[k] != 0.f) {
            float d = exp2f(cnt[k] * P.log1ma);
            a[k][c] = clip01(a[k][c] * d + (1.f - d));
          }
        }
      }
    }
  }
  if (P.f4) {
    #pragma unroll
    for (int k = 0; k < KR; ++k) {
      float4 nv = *reinterpret_cast<const float4*>(
          np_plane + (size_t)(gy0 + k) * NW + gx0);
      a[k][0] = (nv.x < P.thr_lo) ? 0.f : ((nv.x > P.thr_hi) ? 1.f : a[k][0]);
      a[k][1] = (nv.y < P.thr_lo) ? 0.f : ((nv.y > P.thr_hi) ? 1.f : a[k][1]);
      a[k][2] = (nv.z < P.thr_lo) ? 0.f : ((nv.z > P.thr_hi) ? 1.f : a[k][2]);
      a[k][3] = (nv.w < P.thr_lo) ? 0.f : ((nv.w > P.thr_hi) ? 1.f : a[k][3]);
    }
  }
  #pragma unroll
  for (int k = 0; k < KR; ++k)
    *reinterpret_cast<float4*>(op_plane + (size_t)(gy0 + k) * NW + gx0) =
        make_float4(a[k][0], a[k][1], a[k][2], a[k][3]);
}

// ---- fused band kernel (r17 structure + adaptive tap-chunk skipping).
// Blur loops run as 7 static 4-tap chunks; wave-uniform branches skip
// chunks outside the sample's effective support [t_lo,t_hi] (prep-computed,
// skipped mass <1e-3). sigma=1 keeps only 2-3 chunks (-60% blur FMA). ----
__global__ __launch_bounds__(1024, 4)
void fused_kernel(const float* __restrict__ x, const int* __restrict__ flags,
                  const float* __restrict__ wts, const int* __restrict__ order,
                  const int* __restrict__ trange,
                  const float* __restrict__ glare_u, const float* __restrict__ occ_u,
                  const float* __restrict__ rain_alpha_u,
                  const float* __restrict__ noise_u, const float* __restrict__ noise_amt_u,
                  const int* __restrict__ nlist, const unsigned* __restrict__ packed,
                  float* __restrict__ out)
{
  // balanced XCD swizzle: 2 adjacent bands per XCD, rotated per plane.
  const int lb = blockIdx.x;
  const int xcd = lb & 7, j = lb >> 3;        // j in 0..191
  const int pidx = j >> 1, sub = j & 1;       // plane slot 0..95
  const int pl = order[pidx];                 // LPT: blur planes first
  const int grp = (xcd + pl) & 7;
  const int band = (grp << 1) | sub;          // 0..15
  const int b = pl / 3;
  const int y0 = band * BAND;
  const int tid = threadIdx.x;
  const size_t plane = (size_t)pl * PLN;

  __shared__ __align__(16) _Float16 s_hb[HROWS * NW];   // 56 KB

  PParams P = load_params(b, flags, glare_u, occ_u, rain_alpha_u, noise_amt_u);

  if (flags[b * 5] > 0) {
    // ---- phase 1: h-blur rows y0-12 .. y0+43 into LDS (wave-per-row) ----
    float w[KS];
    const float* wp = wts + b * 28;            // wave-uniform -> SGPRs
    #pragma unroll
    for (int jj = 0; jj < KS; ++jj) w[jj] = wp[jj];
    const int t_lo = trange[b * 2 + 0], t_hi = trange[b * 2 + 1];
    const int c0 = t_lo >> 2, c1 = t_hi >> 2;          // tap chunk range
    const int mc0 = t_lo >> 2, mc1 = (t_hi + 3) >> 2;  // m (LDS row) chunks

    const int lane = tid & 63, wv = tid >> 6;  // wv in 0..15
    const int wstart = (lane << 3) - HALF;     // 8*lane - 12 (4-aligned)

    for (int k = 0; k < 4; ++k) {              // 16 waves x <=4 = 56 rows
      const int i = wv + (k << 4);             // LDS row index
      if (i < HROWS) {                         // wave-uniform guard
        const int hy = y0 - HALF + i;          // source image row
        half8 o;
        if ((unsigned)hy < (unsigned)NH) {     // wave-uniform
          const float* rowp = x + plane + (size_t)hy * NW;
          float4 A[8];
          #pragma unroll
          for (int jj = 0; jj < 8; ++jj) {
            int col = wstart + 4 * jj;
            col = max(0, min(col, NW - 4));    // clamp: safe addr
            A[jj] = *reinterpret_cast<const float4*>(rowp + col);
          }
          float win[32];
          #pragma unroll
          for (int jj = 0; jj < 8; ++jj) {
            win[4 * jj + 0] = A[jj].x; win[4 * jj + 1] = A[jj].y;
            win[4 * jj + 2] = A[jj].z; win[4 * jj + 3] = A[jj].w;
          }
          if (lane == 0) {
            #pragma unroll
            for (int ii = 0; ii < 12; ++ii) win[ii] = 0.f;
          }
          if (lane == 1) {
            #pragma unroll
            for (int ii = 0; ii < 4; ++ii) win[ii] = 0.f;
          }
          if (lane == 62) {
            #pragma unroll
            for (int ii = 28; ii < 32; ++ii) win[ii] = 0.f;
          }
          if (lane == 63) {
            #pragma unroll
            for (int ii = 20; ii < 32; ++ii) win[ii] = 0.f;
          }
          float acc[8];
          #pragma unroll
          for (int e = 0; e < 8; ++e) acc[e] = 0.f;
          // 7 static 4-tap chunks; wave-uniform skip outside [c0,c1]
          #pragma unroll
          for (int c = 0; c < 7; ++c) {
            if (c >= c0 && c <= c1) {
              #pragma unroll
              for (int tt = 0; tt < 4; ++tt) {
                constexpr int KSi = KS;
                int t = 4 * c + tt;            // static after unroll
                if (4 * c + tt < KSi) {
                  float wt = w[4 * c + tt];
                  #pragma unroll
                  for (int e = 0; e < 8; ++e)
                    acc[e] = fmaf(wt, win[4 * c + tt + e], acc[e]);
                }
                (void)t;
              }
            }
          }
          #pragma unroll
          for (int e = 0; e < 8; ++e) o[e] = (_Float16)acc[e];
        } else {
          #pragma unroll
          for (int e = 0; e < 8; ++e) o[e] = (_Float16)0.f;   // zero-pad row
        }
        *reinterpret_cast<half8*>(&s_hb[i * NW + (lane << 3)]) = o;
      }
    }
    __syncthreads();

    // ---- phase 2: v-blur from LDS + chain (4 rows x 4 cols per thread) ----
    const int cq = tid & 127, rh = tid >> 7;   // rh in 0..7
    const int gx0 = cq << 2;
    const int gy0 = y0 + (rh << 2);
    float a[4][4];
    #pragma unroll
    for (int k = 0; k < 4; ++k) {
      a[k][0] = 0.f; a[k][1] = 0.f; a[k][2] = 0.f; a[k][3] = 0.f;
    }
    // m in 0..27 as 7 static 4-row chunks; skip chunks with no tap in
    // [t_lo, t_hi+3] (also skips their LDS loads).
    #pragma unroll
    for (int cm = 0; cm < 7; ++cm) {
      if (cm >= mc0 && cm <= mc1) {
        #pragma unroll
        for (int mm = 0; mm < 4; ++mm) {
          const int m = 4 * cm + mm;           // static after unroll
          const int i = (rh << 2) + m;         // LDS row for this tap
          half4 v = *reinterpret_cast<const half4*>(&s_hb[i * NW + gx0]);
          float v0 = (float)v.x, v1 = (float)v.y, v2 = (float)v.z, v3 = (float)v.w;
          #pragma unroll
          for (int k = 0; k < 4; ++k) {
            int wi = m - k;
            if (wi >= 0 && wi <= 24) {
              float wt = w[wi];
              a[k][0] = fmaf(wt, v0, a[k][0]);
              a[k][1] = fmaf(wt, v1, a[k][1]);
              a[k][2] = fmaf(wt, v2, a[k][2]);
              a[k][3] = fmaf(wt, v3, a[k][3]);
            }
          }
        }
      }
    }
    #pragma unroll
    for (int k = 0; k < 4; ++k) {
      a[k][0] = clip01(a[k][0]); a[k][1] = clip01(a[k][1]);
      a[k][2] = clip01(a[k][2]); a[k][3] = clip01(a[k][3]);
    }
    chain_quadN<4>(a, P, b, gx0, gy0, noise_u + plane, nlist, packed, out + plane);
  } else {
    // ---- non-blur plane: pure streaming (no LDS use, no barrier) ----
    const int cq = tid & 127, rh = tid >> 7;
    const int gx0 = cq << 2;
    const int gy0 = y0 + (rh << 2);
    float a[4][4];
    const float* xp = x + plane + gx0;
    #pragma unroll
    for (int k = 0; k < 4; ++k) {
      float4 v = *reinterpret_cast<const float4*>(xp + (size_t)(gy0 + k) * NW);
      a[k][0] = v.x; a[k][1] = v.y; a[k][2] = v.z; a[k][3] = v.w;
    }
    chain_quadN<4>(a, P, b, gx0, gy0, noise_u + plane, nlist, packed, out + plane);
  }
}

// ---- fallback (ws too small): r3's fused single kernel ----
__global__ __launch_bounds__(256, 4)
void fallback_kernel(const float* __restrict__ x, const float* __restrict__ sigma_u,
                     const float* __restrict__ glare_u, const float* __restrict__ occ_u,
                     const float* __restrict__ rain_u, const float* __restrict__ rain_n_u,
                     const float* __restrict__ rain_alpha_u, const float* __restrict__ noise_u,
                     const float* __restrict__ noise_amt_u, const int* __restrict__ flags,
                     float* __restrict__ out)
{
  const int b = blockIdx.z, ch = blockIdx.y;
  const int ty0 = (blockIdx.x >> 3) * 64, tx0 = (blockIdx.x & 7) * 64;
  const int tid = threadIdx.x;
  const int f0 = flags[b * 5] > 0;
  PParams P = load_params(b, flags, glare_u, occ_u, rain_alpha_u, noise_amt_u);
  const float nrain = floorf(20.f + 41.f * rain_n_u[b]);
  const size_t plane = (size_t)(b * NC + ch) * PLN;
  const float* xp = x + plane;
  const float* np = noise_u + plane;
  float* op = out + plane;

  __shared__ __align__(16) float s_hb[88 * 64];

  float wr[KS];
  if (f0) {
    float sig = 1.f + 3.f * sigma_u[b];
    float ninv = -1.f / (2.f * sig * sig);
    float s = 0.f;
    #pragma unroll
    for (int t = 0; t < KS; ++t) {
      float d = (float)t - 12.f;
      wr[t] = __expf(d * d * ninv); s += wr[t];
    }
    float inv = 1.f / s;
    #pragma unroll
    for (int t = 0; t < KS; ++t) wr[t] *= inv;

    for (int i = tid; i < 88 * 16; i += 256) {
      int r = i >> 4, q = i & 15;
      int gy = ty0 + r - HALF;
      float a0 = 0.f, a1 = 0.f, a2 = 0.f, a3 = 0.f;
      if ((unsigned)gy < (unsigned)NH) {
        const float* rowp = xp + (size_t)gy * NW;
        int gx0 = tx0 + q * 4;
        float win[28];
        if (gx0 - HALF >= 0 && gx0 + 15 < NW) {
          #pragma unroll
          for (int j = 0; j < 7; ++j) {
            float4 v = *reinterpret_cast<const float4*>(rowp + gx0 - HALF + 4 * j);
            win[4 * j + 0] = v.x; win[4 * j + 1] = v.y;
            win[4 * j + 2] = v.z; win[4 * j + 3] = v.w;
          }
        } else {
          #pragma unroll
          for (int j = 0; j < 28; ++j) {
            int gx = gx0 - HALF + j;
            win[j] = ((unsigned)gx < (unsigned)NW) ? rowp[gx] : 0.f;
          }
        }
        #pragma unroll
        for (int t = 0; t < KS; ++t) {
          float wt = wr[t];
          a0 = fmaf(wt, win[t + 0], a0);
          a1 = fmaf(wt, win[t + 1], a1);
          a2 = fmaf(wt, win[t + 2], a2);
          a3 = fmaf(wt, win[t + 3], a3);
        }
      }
      *reinterpret_cast<float4*>(&s_hb[r * 64 + (i & 15) * 4]) =
          make_float4(a0, a1, a2, a3);
    }
    __syncthreads();
  }

  for (int i = tid; i < 512; i += 256) {
    int xq = i & 63, sy = i >> 6;
    int gx = tx0 + xq, gy0 = ty0 + sy * 8;
    float acc[8];
    if (f0) {
      float wincol[32];
      #pragma unroll
      for (int j = 0; j < 32; ++j) wincol[j] = s_hb[(sy * 8 + j) * 64 + xq];
      #pragma unroll
      for (int k = 0; k < 8; ++k) {
        float a = 0.f;
        #pragma unroll
        for (int t = 0; t < KS; ++t) a = fmaf(wr[t], wincol[k + t], a);
        acc[k] = clip01(a);
      }
    } else {
      #pragma unroll
      for (int k = 0; k < 8; ++k) acc[k] = xp[(size_t)(gy0 + k) * NW + gx];
    }
    const float fx = (float)gx;
    if (P.f1) {
      float dx = (fx - P.cx) * P.rxi;
      float dx2 = dx * dx;
      #pragma unroll
      for (int k = 0; k < 8; ++k) {
        float dy = ((float)(gy0 + k) - P.cy) * P.ryi;
        acc[k] = clip01(acc[k] + P.intensity * __expf(-(dx2 + dy * dy)));
      }
    }
    if (P.f2 && fx >= P.ox0 && fx < P.ox1) {
      #pragma unroll
      for (int k = 0; k < 8; ++k) {
        float fy = (float)(gy0 + k);
        if (fy >= P.oy0 && fy < P.oy1) acc[k] = 0.f;
      }
    }
    if (P.f3) {
      float cnt[8];
      #pragma unroll
      for (int k = 0; k < 8; ++k) cnt[k] = 0.f;
      for (int s = 0; s < NS; ++s) {
        if ((float)s < nrain) {
          float xc = floorf(rain_u[(b * NS + s) * 3 + 0] * 512.f);
          if (fx >= xc - 1.f && fx <= xc) {
            float y0 = floorf(rain_u[(b * NS + s) * 3 + 1] * 256.f);
            float y1 = 256.f + floorf(rain_u[(b * NS + s) * 3 + 2] * 256.f);
            #pragma unroll
            for (int k = 0; k < 8; ++k) {
              float fy = (float)(gy0 + k);
              cnt[k] += (fy >= y0 && fy < y1) ? 1.f : 0.f;
            }
          }
        }
      }
      #pragma unroll
      for (int k = 0; k < 8; ++k) {
        if (cnt[k] != 0.f) {
          float d = exp2f(cnt[k] * P.log1ma);
          acc[k] = clip01(acc[k] * d + (1.f - d));
        }
      }
    }
    if (P.f4) {
      #pragma unroll
      for (int k = 0; k < 8; ++k) {
        float nv = np[(size_t)(gy0 + k) * NW + gx];
        acc[k] = (nv < P.thr_lo) ? 0.f : ((nv > P.thr_hi) ? 1.f : acc[k]);
      }
    }
    #pragma unroll
    for (int k = 0; k < 8; ++k) op[(size_t)(gy0 + k) * NW + gx] = acc[k];
  }
}

extern "C" void kernel_launch(void* const* d_in, const int* in_sizes, int n_in,
                              void* d_out, int out_size, void* d_ws, size_t ws_size,
                              hipStream_t stream)
{
  const float* x            = (const float*)d_in[0];
  const float* sigma_u      = (const float*)d_in[1];
  const float* glare_u      = (const float*)d_in[2];
  const float* occ_u        = (const float*)d_in[3];
  const float* rain_u       = (const float*)d_in[4];
  const float* rain_n_u     = (const float*)d_in[5];
  const float* rain_alpha_u = (const float*)d_in[6];
  const float* noise_u      = (const float*)d_in[7];
  const float* noise_amt_u  = (const float*)d_in[8];
  const int*   flags        = (const int*)d_in[9];
  float* out = (float*)d_out;

  if (ws_size >= WS_NEED) {
    float*    wts    = (float*)((char*)d_ws + WTS_OFF);
    int*      order  = (int*)((char*)d_ws + ORD_OFF);
    int*      trange = (int*)((char*)d_ws + TR_OFF);
    int*      nlist  = (int*)((char*)d_ws + NL_OFF);
    unsigned* packed = (unsigned*)((char*)d_ws + PK_OFF);

    prep_kernel<<<65, 256, 0, stream>>>(rain_u, rain_n_u, sigma_u, flags,
                                        nlist, packed, wts, order, trange);
    fused_kernel<<<NPL * NBANDS, 1024, 0, stream>>>(
        x, flags, wts, order, trange, glare_u, occ_u, rain_alpha_u, noise_u,
        noise_amt_u, nlist, packed, out);
  } else {
    dim3 grid(64, NC, NB);
    fallback_kernel<<<grid, 256, 0, stream>>>(
        x, sigma_u, glare_u, occ_u, rain_u, rain_n_u, rain_alpha_u,
        noise_u, noise_amt_u, flags, out);
  }
}

// Round 19
// 82.624 us; speedup vs baseline: 1.1065x; 1.1065x over previous
//
#include <hip/hip_runtime.h>

#define NB   32
#define NC   3
#define NH   512
#define NW   512
#define KS   25
#define HALF 12
#define NS   60
#define PLN  (NH * NW)        // 262144
#define NPL  (NB * NC)        // 96
#define BAND 32               // output rows per block
#define HROWS (BAND + 2 * HALF)   // 56 h-blurred rows staged in LDS
#define NBANDS (NH / BAND)    // 16

typedef _Float16 half4 __attribute__((ext_vector_type(4)));
typedef _Float16 half8 __attribute__((ext_vector_type(8)));

// ---- workspace layout ----
#define WTS_OFF   ((size_t)0)
#define WTS_BYTES ((size_t)4096)
#define ORD_OFF   (WTS_OFF + WTS_BYTES)
#define ORD_BYTES ((size_t)512)               // 96 ints, padded
#define NL_OFF    (ORD_OFF + ORD_BYTES)
#define NL_BYTES  ((size_t)NB * NW * 4)
#define PK_OFF    (NL_OFF + NL_BYTES)
#define PK_BYTES  ((size_t)NB * NW * NS * 4)
#define WS_NEED   (PK_OFF + PK_BYTES)                 // ~4.3 MB

__device__ __forceinline__ float clip01(float v) { return fminf(fmaxf(v, 0.f), 1.f); }

struct PParams {
  int f1, f2, f3, f4;
  float intensity, cx, cy, rxi, ryi;
  float oy0, oy1, ox0, ox1;
  float log1ma;
  float thr_lo, thr_hi;
};

__device__ __forceinline__ PParams load_params(
    int b, const int* __restrict__ flags, const float* __restrict__ glare_u,
    const float* __restrict__ occ_u, const float* __restrict__ rain_alpha_u,
    const float* __restrict__ noise_amt_u)
{
  PParams P;
  P.f1 = flags[b * 5 + 1] > 0;
  P.f2 = flags[b * 5 + 2] > 0;
  P.f3 = flags[b * 5 + 3] > 0;
  P.f4 = flags[b * 5 + 4] > 0;
  float g0 = glare_u[b * 5 + 0], g1 = glare_u[b * 5 + 1], g2 = glare_u[b * 5 + 2],
        g3 = glare_u[b * 5 + 3], g4 = glare_u[b * 5 + 4];
  P.intensity = 0.4f + 0.5f * g0;
  P.rxi = 1.f / ((0.1f + 0.25f * g1) * 256.f);
  P.ryi = 1.f / ((0.1f + 0.25f * g2) * 256.f);
  P.cx = (0.2f + 0.6f * g3) * 512.f;
  P.cy = (0.2f + 0.6f * g4) * 512.f;
  float o0 = occ_u[b * 4 + 0], o1 = occ_u[b * 4 + 1],
        o2 = occ_u[b * 4 + 2], o3 = occ_u[b * 4 + 3];
  float ph = floorf(512.f * (0.1f + 0.3f * o0));
  float pw = floorf(512.f * (0.1f + 0.3f * o1));
  P.oy0 = floorf(o2 * (512.f - ph)); P.oy1 = P.oy0 + ph;
  P.ox0 = floorf(o3 * (512.f - pw)); P.ox1 = P.ox0 + pw;
  P.log1ma = log2f(1.f - (0.15f + 0.35f * rain_alpha_u[b]));
  float half_amt = 0.5f * (0.01f + 0.07f * noise_amt_u[b]);
  P.thr_lo = half_amt; P.thr_hi = 1.f - half_amt;
  return P;
}

// ---- prep: rain column lists + per-sample blur weights + LPT plane order ----
__global__ void prep_kernel(const float* __restrict__ rain_u,
                            const float* __restrict__ rain_n_u,
                            const float* __restrict__ sigma_u,
                            const int* __restrict__ flags,
                            int* __restrict__ nlist,
                            unsigned* __restrict__ packed,
                            float* __restrict__ wts,
                            int* __restrict__ order)
{
  if (blockIdx.x == 64) {
    int b = threadIdx.x;
    if (b < NB) {
      float sig = 1.f + 3.f * sigma_u[b];
      float ninv = -1.f / (2.f * sig * sig);
      float w[KS]; float s = 0.f;
      #pragma unroll
      for (int j = 0; j < KS; ++j) {
        float d = (float)j - 12.f;
        w[j] = __expf(d * d * ninv);
        s += w[j];
      }
      float inv = 1.f / s;
      #pragma unroll
      for (int j = 0; j < KS; ++j) wts[b * 28 + j] = w[j] * inv;
    }
    // LPT plane ordering: blur planes first (long blocks dispatched first,
    // short non-blur blocks backfill the tail). Single-thread scan of 96.
    if (threadIdx.x == 64) {
      int pos = 0;
      for (int pl = 0; pl < NPL; ++pl)
        if (flags[(pl / 3) * 5] > 0) order[pos++] = pl;
      for (int pl = 0; pl < NPL; ++pl)
        if (flags[(pl / 3) * 5] <= 0) order[pos++] = pl;
    }
    return;
  }
  int t = blockIdx.x * 256 + threadIdx.x;
  if (t >= NB * NW) return;
  int b = t >> 9, wcol = t & 511;
  float n = floorf(20.f + 41.f * rain_n_u[b]);
  float wf = (float)wcol;
  int cnt = 0;
  for (int s = 0; s < NS; ++s) {
    if ((float)s < n) {
      float xc = floorf(rain_u[(b * NS + s) * 3 + 0] * 512.f);
      if (wf >= xc - 1.f && wf <= xc) {
        float y0 = floorf(rain_u[(b * NS + s) * 3 + 1] * 256.f);
        float y1 = 256.f + floorf(rain_u[(b * NS + s) * 3 + 2] * 256.f);
        packed[t * NS + cnt] = (((unsigned)y0) << 16) | (unsigned)y1;
        ++cnt;
      }
    }
  }
  nlist[t] = cnt;
}

// ---- chain on a 4-col x KR-row quad block ----
template<int KR>
__device__ __forceinline__ void chain_quadN(
    float (&a)[KR][4], const PParams& P, int b, int gx0, int gy0,
    const float* __restrict__ np_plane, const int* __restrict__ nlist,
    const unsigned* __restrict__ packed, float* __restrict__ op_plane)
{
  if (P.f1) {
    float dx2[4];
    #pragma unroll
    for (int c = 0; c < 4; ++c) {
      float dx = ((float)(gx0 + c) - P.cx) * P.rxi;
      dx2[c] = dx * dx;
    }
    #pragma unroll
    for (int k = 0; k < KR; ++k) {
      float dy = ((float)(gy0 + k) - P.cy) * P.ryi;
      float dy2 = dy * dy;
      #pragma unroll
      for (int c = 0; c < 4; ++c) {
        float g = __expf(-(dx2[c] + dy2));
        a[k][c] = clip01(a[k][c] + P.intensity * g);
      }
    }
  }
  if (P.f2) {
    #pragma unroll
    for (int c = 0; c < 4; ++c) {
      float fx = (float)(gx0 + c);
      if (fx >= P.ox0 && fx < P.ox1) {
        #pragma unroll
        for (int k = 0; k < KR; ++k) {
          float fy = (float)(gy0 + k);
          if (fy >= P.oy0 && fy < P.oy1) a[k][c] = 0.f;
        }
      }
    }
  }
  if (P.f3) {
    #pragma unroll
    for (int c = 0; c < 4; ++c) {
      int base = b * NW + gx0 + c;
      int n = nlist[base];
      if (n > 0) {
        float cnt[KR];
        #pragma unroll
        for (int k = 0; k < KR; ++k) cnt[k] = 0.f;
        for (int j = 0; j < n; ++j) {
          unsigned p = packed[base * NS + j];
          float y0 = (float)(p >> 16), y1 = (float)(p & 0xffffu);
          #pragma unroll
          for (int k = 0; k < KR; ++k) {
            float fy = (float)(gy0 + k);
            cnt[k] += (fy >= y0 && fy < y1) ? 1.f : 0.f;
          }
        }
        #pragma unroll
        for (int k = 0; k < KR; ++k) {
          if (cnt[k] != 0.f) {
            float d = exp2f(cnt[k] * P.log1ma);
            a[k][c] = clip01(a[k][c] * d + (1.f - d));
          }
        }
      }
    }
  }
  if (P.f4) {
    #pragma unroll
    for (int k = 0; k < KR; ++k) {
      float4 nv = *reinterpret_cast<const float4*>(
          np_plane + (size_t)(gy0 + k) * NW + gx0);
      a[k][0] = (nv.x < P.thr_lo) ? 0.f : ((nv.x > P.thr_hi) ? 1.f : a[k][0]);
      a[k][1] = (nv.y < P.thr_lo) ? 0.f : ((nv.y > P.thr_hi) ? 1.f : a[k][1]);
      a[k][2] = (nv.z < P.thr_lo) ? 0.f : ((nv.z > P.thr_hi) ? 1.f : a[k][2]);
      a[k][3] = (nv.w < P.thr_lo) ? 0.f : ((nv.w > P.thr_hi) ? 1.f : a[k][3]);
    }
  }
  #pragma unroll
  for (int k = 0; k < KR; ++k)
    *reinterpret_cast<float4*>(op_plane + (size_t)(gy0 + k) * NW + gx0) =
        make_float4(a[k][0], a[k][1], a[k][2], a[k][3]);
}

// ---- fused band kernel, 1024 threads, BAND=32 (r16 bodies verbatim).
// Plane index comes from the LPT order[] (blur planes first): blocks are
// dispatched roughly in blockIdx order, so the ~8x-longer blur blocks
// start early and short non-blur blocks backfill the drain tail.
// r18's adaptive tap-chunking REVERTED: branch-guarded chunks broke the
// flat load/FMA pipeline (dur 105->111 despite VALUBusy 38->34). ----
__global__ __launch_bounds__(1024, 4)
void fused_kernel(const float* __restrict__ x, const int* __restrict__ flags,
                  const float* __restrict__ wts, const int* __restrict__ order,
                  const float* __restrict__ glare_u, const float* __restrict__ occ_u,
                  const float* __restrict__ rain_alpha_u,
                  const float* __restrict__ noise_u, const float* __restrict__ noise_amt_u,
                  const int* __restrict__ nlist, const unsigned* __restrict__ packed,
                  float* __restrict__ out)
{
  // balanced XCD swizzle: 2 adjacent bands per XCD, rotated per plane.
  const int lb = blockIdx.x;
  const int xcd = lb & 7, j = lb >> 3;        // j in 0..191
  const int pidx = j >> 1, sub = j & 1;       // plane slot 0..95
  const int pl = order[pidx];                 // LPT: blur planes first
  const int grp = (xcd + pl) & 7;
  const int band = (grp << 1) | sub;          // 0..15
  const int b = pl / 3;
  const int y0 = band * BAND;
  const int tid = threadIdx.x;
  const size_t plane = (size_t)pl * PLN;

  __shared__ __align__(16) _Float16 s_hb[HROWS * NW];   // 56 KB

  PParams P = load_params(b, flags, glare_u, occ_u, rain_alpha_u, noise_amt_u);

  if (flags[b * 5] > 0) {
    // ---- phase 1: h-blur rows y0-12 .. y0+43 into LDS (wave-per-row) ----
    float w[KS];
    const float* wp = wts + b * 28;            // wave-uniform -> SGPRs
    #pragma unroll
    for (int jj = 0; jj < KS; ++jj) w[jj] = wp[jj];

    const int lane = tid & 63, wv = tid >> 6;  // wv in 0..15
    const int wstart = (lane << 3) - HALF;     // 8*lane - 12 (4-aligned)

    for (int k = 0; k < 4; ++k) {              // 16 waves x <=4 = 56 rows
      const int i = wv + (k << 4);             // LDS row index
      if (i < HROWS) {                         // wave-uniform guard
        const int hy = y0 - HALF + i;          // source image row
        half8 o;
        if ((unsigned)hy < (unsigned)NH) {     // wave-uniform
          const float* rowp = x + plane + (size_t)hy * NW;
          float4 A[8];
          #pragma unroll
          for (int jj = 0; jj < 8; ++jj) {
            int col = wstart + 4 * jj;
            col = max(0, min(col, NW - 4));    // clamp: safe addr
            A[jj] = *reinterpret_cast<const float4*>(rowp + col);
          }
          float win[32];
          #pragma unroll
          for (int jj = 0; jj < 8; ++jj) {
            win[4 * jj + 0] = A[jj].x; win[4 * jj + 1] = A[jj].y;
            win[4 * jj + 2] = A[jj].z; win[4 * jj + 3] = A[jj].w;
          }
          if (lane == 0) {
            #pragma unroll
            for (int ii = 0; ii < 12; ++ii) win[ii] = 0.f;
          }
          if (lane == 1) {
            #pragma unroll
            for (int ii = 0; ii < 4; ++ii) win[ii] = 0.f;
          }
          if (lane == 62) {
            #pragma unroll
            for (int ii = 28; ii < 32; ++ii) win[ii] = 0.f;
          }
          if (lane == 63) {
            #pragma unroll
            for (int ii = 20; ii < 32; ++ii) win[ii] = 0.f;
          }
          float acc[8];
          #pragma unroll
          for (int e = 0; e < 8; ++e) acc[e] = 0.f;
          #pragma unroll
          for (int t = 0; t < KS; ++t) {
            float wt = w[t];
            #pragma unroll
            for (int e = 0; e < 8; ++e) acc[e] = fmaf(wt, win[t + e], acc[e]);
          }
          #pragma unroll
          for (int e = 0; e < 8; ++e) o[e] = (_Float16)acc[e];
        } else {
          #pragma unroll
          for (int e = 0; e < 8; ++e) o[e] = (_Float16)0.f;   // zero-pad row
        }
        *reinterpret_cast<half8*>(&s_hb[i * NW + (lane << 3)]) = o;
      }
    }
    __syncthreads();

    // ---- phase 2: v-blur from LDS + chain (4 rows x 4 cols per thread) ----
    const int cq = tid & 127, rh = tid >> 7;   // rh in 0..7
    const int gx0 = cq << 2;
    const int gy0 = y0 + (rh << 2);
    float a[4][4];
    #pragma unroll
    for (int k = 0; k < 4; ++k) {
      a[k][0] = 0.f; a[k][1] = 0.f; a[k][2] = 0.f; a[k][3] = 0.f;
    }
    #pragma unroll
    for (int m = 0; m < 28; ++m) {
      const int i = (rh << 2) + m;             // LDS row for this tap
      half4 v = *reinterpret_cast<const half4*>(&s_hb[i * NW + gx0]);
      float v0 = (float)v.x, v1 = (float)v.y, v2 = (float)v.z, v3 = (float)v.w;
      #pragma unroll
      for (int k = 0; k < 4; ++k) {
        int wi = m - k;
        if (wi >= 0 && wi <= 24) {
          float wt = w[wi];
          a[k][0] = fmaf(wt, v0, a[k][0]);
          a[k][1] = fmaf(wt, v1, a[k][1]);
          a[k][2] = fmaf(wt, v2, a[k][2]);
          a[k][3] = fmaf(wt, v3, a[k][3]);
        }
      }
    }
    #pragma unroll
    for (int k = 0; k < 4; ++k) {
      a[k][0] = clip01(a[k][0]); a[k][1] = clip01(a[k][1]);
      a[k][2] = clip01(a[k][2]); a[k][3] = clip01(a[k][3]);
    }
    chain_quadN<4>(a, P, b, gx0, gy0, noise_u + plane, nlist, packed, out + plane);
  } else {
    // ---- non-blur plane: pure streaming (no LDS use, no barrier) ----
    const int cq = tid & 127, rh = tid >> 7;
    const int gx0 = cq << 2;
    const int gy0 = y0 + (rh << 2);
    float a[4][4];
    const float* xp = x + plane + gx0;
    #pragma unroll
    for (int k = 0; k < 4; ++k) {
      float4 v = *reinterpret_cast<const float4*>(xp + (size_t)(gy0 + k) * NW);
      a[k][0] = v.x; a[k][1] = v.y; a[k][2] = v.z; a[k][3] = v.w;
    }
    chain_quadN<4>(a, P, b, gx0, gy0, noise_u + plane, nlist, packed, out + plane);
  }
}

// ---- fallback (ws too small): r3's fused single kernel ----
__global__ __launch_bounds__(256, 4)
void fallback_kernel(const float* __restrict__ x, const float* __restrict__ sigma_u,
                     const float* __restrict__ glare_u, const float* __restrict__ occ_u,
                     const float* __restrict__ rain_u, const float* __restrict__ rain_n_u,
                     const float* __restrict__ rain_alpha_u, const float* __restrict__ noise_u,
                     const float* __restrict__ noise_amt_u, const int* __restrict__ flags,
                     float* __restrict__ out)
{
  const int b = blockIdx.z, ch = blockIdx.y;
  const int ty0 = (blockIdx.x >> 3) * 64, tx0 = (blockIdx.x & 7) * 64;
  const int tid = threadIdx.x;
  const int f0 = flags[b * 5] > 0;
  PParams P = load_params(b, flags, glare_u, occ_u, rain_alpha_u, noise_amt_u);
  const float nrain = floorf(20.f + 41.f * rain_n_u[b]);
  const size_t plane = (size_t)(b * NC + ch) * PLN;
  const float* xp = x + plane;
  const float* np = noise_u + plane;
  float* op = out + plane;

  __shared__ __align__(16) float s_hb[88 * 64];

  float wr[KS];
  if (f0) {
    float sig = 1.f + 3.f * sigma_u[b];
    float ninv = -1.f / (2.f * sig * sig);
    float s = 0.f;
    #pragma unroll
    for (int t = 0; t < KS; ++t) {
      float d = (float)t - 12.f;
      wr[t] = __expf(d * d * ninv); s += wr[t];
    }
    float inv = 1.f / s;
    #pragma unroll
    for (int t = 0; t < KS; ++t) wr[t] *= inv;

    for (int i = tid; i < 88 * 16; i += 256) {
      int r = i >> 4, q = i & 15;
      int gy = ty0 + r - HALF;
      float a0 = 0.f, a1 = 0.f, a2 = 0.f, a3 = 0.f;
      if ((unsigned)gy < (unsigned)NH) {
        const float* rowp = xp + (size_t)gy * NW;
        int gx0 = tx0 + q * 4;
        float win[28];
        if (gx0 - HALF >= 0 && gx0 + 15 < NW) {
          #pragma unroll
          for (int j = 0; j < 7; ++j) {
            float4 v = *reinterpret_cast<const float4*>(rowp + gx0 - HALF + 4 * j);
            win[4 * j + 0] = v.x; win[4 * j + 1] = v.y;
            win[4 * j + 2] = v.z; win[4 * j + 3] = v.w;
          }
        } else {
          #pragma unroll
          for (int j = 0; j < 28; ++j) {
            int gx = gx0 - HALF + j;
            win[j] = ((unsigned)gx < (unsigned)NW) ? rowp[gx] : 0.f;
          }
        }
        #pragma unroll
        for (int t = 0; t < KS; ++t) {
          float wt = wr[t];
          a0 = fmaf(wt, win[t + 0], a0);
          a1 = fmaf(wt, win[t + 1], a1);
          a2 = fmaf(wt, win[t + 2], a2);
          a3 = fmaf(wt, win[t + 3], a3);
        }
      }
      *reinterpret_cast<float4*>(&s_hb[r * 64 + (i & 15) * 4]) =
          make_float4(a0, a1, a2, a3);
    }
    __syncthreads();
  }

  for (int i = tid; i < 512; i += 256) {
    int xq = i & 63, sy = i >> 6;
    int gx = tx0 + xq, gy0 = ty0 + sy * 8;
    float acc[8];
    if (f0) {
      float wincol[32];
      #pragma unroll
      for (int j = 0; j < 32; ++j) wincol[j] = s_hb[(sy * 8 + j) * 64 + xq];
      #pragma unroll
      for (int k = 0; k < 8; ++k) {
        float a = 0.f;
        #pragma unroll
        for (int t = 0; t < KS; ++t) a = fmaf(wr[t], wincol[k + t], a);
        acc[k] = clip01(a);
      }
    } else {
      #pragma unroll
      for (int k = 0; k < 8; ++k) acc[k] = xp[(size_t)(gy0 + k) * NW + gx];
    }
    const float fx = (float)gx;
    if (P.f1) {
      float dx = (fx - P.cx) * P.rxi;
      float dx2 = dx * dx;
      #pragma unroll
      for (int k = 0; k < 8; ++k) {
        float dy = ((float)(gy0 + k) - P.cy) * P.ryi;
        acc[k] = clip01(acc[k] + P.intensity * __expf(-(dx2 + dy * dy)));
      }
    }
    if (P.f2 && fx >= P.ox0 && fx < P.ox1) {
      #pragma unroll
      for (int k = 0; k < 8; ++k) {
        float fy = (float)(gy0 + k);
        if (fy >= P.oy0 && fy < P.oy1) acc[k] = 0.f;
      }
    }
    if (P.f3) {
      float cnt[8];
      #pragma unroll
      for (int k = 0; k < 8; ++k) cnt[k] = 0.f;
      for (int s = 0; s < NS; ++s) {
        if ((float)s < nrain) {
          float xc = floorf(rain_u[(b * NS + s) * 3 + 0] * 512.f);
          if (fx >= xc - 1.f && fx <= xc) {
            float y0 = floorf(rain_u[(b * NS + s) * 3 + 1] * 256.f);
            float y1 = 256.f + floorf(rain_u[(b * NS + s) * 3 + 2] * 256.f);
            #pragma unroll
            for (int k = 0; k < 8; ++k) {
              float fy = (float)(gy0 + k);
              cnt[k] += (fy >= y0 && fy < y1) ? 1.f : 0.f;
            }
          }
        }
      }
      #pragma unroll
      for (int k = 0; k < 8; ++k) {
        if (cnt[k] != 0.f) {
          float d = exp2f(cnt[k] * P.log1ma);
          acc[k] = clip01(acc[k] * d + (1.f - d));
        }
      }
    }
    if (P.f4) {
      #pragma unroll
      for (int k = 0; k < 8; ++k) {
        float nv = np[(size_t)(gy0 + k) * NW + gx];
        acc[k] = (nv < P.thr_lo) ? 0.f : ((nv > P.thr_hi) ? 1.f : acc[k]);
      }
    }
    #pragma unroll
    for (int k = 0; k < 8; ++k) op[(size_t)(gy0 + k) * NW + gx] = acc[k];
  }
}

extern "C" void kernel_launch(void* const* d_in, const int* in_sizes, int n_in,
                              void* d_out, int out_size, void* d_ws, size_t ws_size,
                              hipStream_t stream)
{
  const float* x            = (const float*)d_in[0];
  const float* sigma_u      = (const float*)d_in[1];
  const float* glare_u      = (const float*)d_in[2];
  const float* occ_u        = (const float*)d_in[3];
  const float* rain_u       = (const float*)d_in[4];
  const float* rain_n_u     = (const float*)d_in[5];
  const float* rain_alpha_u = (const float*)d_in[6];
  const float* noise_u      = (const float*)d_in[7];
  const float* noise_amt_u  = (const float*)d_in[8];
  const int*   flags        = (const int*)d_in[9];
  float* out = (float*)d_out;

  if (ws_size >= WS_NEED) {
    float*    wts    = (float*)((char*)d_ws + WTS_OFF);
    int*      order  = (int*)((char*)d_ws + ORD_OFF);
    int*      nlist  = (int*)((char*)d_ws + NL_OFF);
    unsigned* packed = (unsigned*)((char*)d_ws + PK_OFF);

    prep_kernel<<<65, 256, 0, stream>>>(rain_u, rain_n_u, sigma_u, flags,
                                        nlist, packed, wts, order);
    fused_kernel<<<NPL * NBANDS, 1024, 0, stream>>>(
        x, flags, wts, order, glare_u, occ_u, rain_alpha_u, noise_u,
        noise_amt_u, nlist, packed, out);
  } else {
    dim3 grid(64, NC, NB);
    fallback_kernel<<<grid, 256, 0, stream>>>(
        x, sigma_u, glare_u, occ_u, rain_u, rain_n_u, rain_alpha_u,
        noise_u, noise_amt_u, flags, out);
  }
}